// Round 2
// baseline (1044.817 us; speedup 1.0000x reference)
//
#include <hip/hip_runtime.h>
#include <hip/hip_bf16.h>

// Problem constants (fixed by setup_inputs)
#define BB 1024
#define SS 1024
#define DIN 128
#define DSLOT 64
#define TOPK 8
#define TOKENS (BB*SS)          // 1048576

// ---- bf16 helpers (manual, RNE) ----
__device__ __forceinline__ unsigned short f2bf(float x) {
    unsigned u = __float_as_uint(x);
    return (unsigned short)((u + 0x7fffu + ((u >> 16) & 1u)) >> 16);
}
__device__ __forceinline__ float bf2f(unsigned u16) {
    return __uint_as_float(u16 << 16);
}

// ------------------------------------------------------------------
// prep: vv[d] = sum_j W2[d][j]*qm[j], qm[j]=(q0[j]+q1[j])*0.5*0.125; vv[64]=b2.qm
// ------------------------------------------------------------------
__global__ void prep_kernel(const float* __restrict__ W2, const float* __restrict__ b2,
                            const float* __restrict__ q, float* __restrict__ vv) {
    __shared__ float qm[64];
    int d = threadIdx.x;
    if (d < 64) qm[d] = (q[d] + q[64 + d]) * 0.0625f;
    __syncthreads();
    if (d < 64) {
        float acc = 0.f;
        #pragma unroll
        for (int j = 0; j < 64; ++j) acc = fmaf(W2[d * 64 + j], qm[j], acc);
        vv[d] = acc;
    }
    if (d == 0) {
        float c = 0.f;
        for (int j = 0; j < 64; ++j) c = fmaf(b2[j], qm[j], c);
        vv[64] = c;
    }
}

// ------------------------------------------------------------------
// MLP + score. 256 threads = 256 tokens per block; one token per thread,
// all 64 channels in registers. Weights are read with wave-uniform addresses
// -> scalar loads (s_load) -> zero LDS/VGPR traffic for weights.
// ------------------------------------------------------------------
__global__ __launch_bounds__(256, 4) void mlp_kernel(
    const float* __restrict__ feats, const float* __restrict__ W1,
    const float* __restrict__ b1, const float* __restrict__ W2,
    const float* __restrict__ b2, const float* __restrict__ vv,
    unsigned short* __restrict__ Hws, float* __restrict__ scores)
{
    __shared__ float Xs[256][33];                 // 33.8 KB; reused as packed-h and out buffer
    unsigned* Hp = (unsigned*)&Xs[0][0];          // row stride 33 uints

    const int tid = threadIdx.x;
    const long t0 = (long)blockIdx.x * 256;

    float acc[64];
    #pragma unroll
    for (int j = 0; j < 64; ++j) acc[j] = 0.f;

    // ---- layer 1: K = 128, staged in 4 chunks of 32 cols ----
    #pragma unroll 1
    for (int kc = 0; kc < 4; ++kc) {
        __syncthreads();  // previous chunk fully consumed
        #pragma unroll
        for (int i = 0; i < 8; ++i) {
            int li = tid + i * 256;               // 0..2047
            int row = li >> 3, c4 = li & 7;
            float4 f = *(const float4*)&feats[(t0 + row) * DIN + kc * 32 + c4 * 4];
            Xs[row][c4 * 4 + 0] = f.x; Xs[row][c4 * 4 + 1] = f.y;
            Xs[row][c4 * 4 + 2] = f.z; Xs[row][c4 * 4 + 3] = f.w;
        }
        __syncthreads();
        #pragma unroll 1
        for (int kq = 0; kq < 8; ++kq) {
            float x0 = Xs[tid][kq * 4 + 0];
            float x1 = Xs[tid][kq * 4 + 1];
            float x2 = Xs[tid][kq * 4 + 2];
            float x3 = Xs[tid][kq * 4 + 3];
            const int kk = kc * 32 + kq * 4;
            const float* w0 = W1 + (kk + 0) * DSLOT;
            const float* w1 = W1 + (kk + 1) * DSLOT;
            const float* w2 = W1 + (kk + 2) * DSLOT;
            const float* w3 = W1 + (kk + 3) * DSLOT;
            #pragma unroll
            for (int j = 0; j < 64; ++j) {
                acc[j] = fmaf(x0, w0[j], acc[j]);
                acc[j] = fmaf(x1, w1[j], acc[j]);
                acc[j] = fmaf(x2, w2[j], acc[j]);
                acc[j] = fmaf(x3, w3[j], acc[j]);
            }
        }
    }

    // bias+relu, score, pack h (bf16x2) into OWN LDS row (no barrier needed:
    // every thread only ever reads its own row during compute)
    float score = 0.f;
    #pragma unroll
    for (int j2 = 0; j2 < 32; ++j2) {
        float h0 = fmaxf(acc[2 * j2 + 0] + b1[2 * j2 + 0], 0.f);
        float h1 = fmaxf(acc[2 * j2 + 1] + b1[2 * j2 + 1], 0.f);
        score = fmaf(h0, vv[2 * j2 + 0], score);
        score = fmaf(h1, vv[2 * j2 + 1], score);
        Hp[tid * 33 + j2] = (unsigned)f2bf(h0) | ((unsigned)f2bf(h1) << 16);
    }
    scores[t0 + tid] = score + vv[64];

    // ---- layer 2: K = 64, h streamed from own LDS row ----
    float acc2[64];
    #pragma unroll
    for (int j = 0; j < 64; ++j) acc2[j] = b2[j];

    #pragma unroll 1
    for (int kq = 0; kq < 16; ++kq) {
        unsigned p0 = Hp[tid * 33 + kq * 2 + 0];
        unsigned p1 = Hp[tid * 33 + kq * 2 + 1];
        float h0 = bf2f(p0 & 0xffffu), h1 = bf2f(p0 >> 16);
        float h2 = bf2f(p1 & 0xffffu), h3 = bf2f(p1 >> 16);
        const int kk = kq * 4;
        const float* w0 = W2 + (kk + 0) * DSLOT;
        const float* w1 = W2 + (kk + 1) * DSLOT;
        const float* w2 = W2 + (kk + 2) * DSLOT;
        const float* w3 = W2 + (kk + 3) * DSLOT;
        #pragma unroll
        for (int j = 0; j < 64; ++j) {
            acc2[j] = fmaf(h0, w0[j], acc2[j]);
            acc2[j] = fmaf(h1, w1[j], acc2[j]);
            acc2[j] = fmaf(h2, w2[j], acc2[j]);
            acc2[j] = fmaf(h3, w3[j], acc2[j]);
        }
    }

    // pack H (bf16) into own LDS row, then coalesced block copy to global
    #pragma unroll
    for (int j2 = 0; j2 < 32; ++j2)
        Hp[tid * 33 + j2] = (unsigned)f2bf(acc2[2 * j2 + 0]) | ((unsigned)f2bf(acc2[2 * j2 + 1]) << 16);
    __syncthreads();

    uint2* dst = (uint2*)(Hws + t0 * DSLOT);      // 256*64 bf16 = 4096 uint2
    #pragma unroll
    for (int i = 0; i < 16; ++i) {
        int g0 = (tid + i * 256) * 2;             // even uint index in [0,8192)
        int r = g0 >> 5, c = g0 & 31;
        dst[tid + i * 256] = make_uint2(Hp[r * 33 + c], Hp[r * 33 + c + 1]);
    }
}

// ------------------------------------------------------------------
// Per-batch-row: masked softmax -> attnW, top-8 via packed u64 wave reductions,
// sel gather, ctx = attnW . H
// ------------------------------------------------------------------
__global__ __launch_bounds__(256, 4) void attn_kernel(
    const float* __restrict__ scores, const float* __restrict__ mask,
    const unsigned short* __restrict__ Hws,
    float* __restrict__ out_sel, float* __restrict__ out_ctx, float* __restrict__ out_attn)
{
    const int b = blockIdx.x, tid = threadIdx.x;
    const int lane = tid & 63, wave = tid >> 6;
    __shared__ float ex[SS];
    __shared__ float cred[SS];
    __shared__ float wred[4];
    __shared__ unsigned long long kred[4];
    __shared__ int selIdx[TOPK];

    const float* srow = scores + (long)b * SS;
    const float* mrow = mask + (long)b * SS;

    // load 4 scores per thread, masked
    float sv[4]; bool any = false;
    #pragma unroll
    for (int k = 0; k < 4; ++k) {
        int i = tid + k * 256;
        bool v = mrow[i] > 0.5f;
        sv[k] = v ? srow[i] : -__builtin_inff();
        any |= v;
    }
    unsigned long long ball = __ballot(any);
    if (lane == 0) kred[wave] = ball;
    __syncthreads();
    const bool av = (kred[0] | kred[1] | kred[2] | kred[3]) != 0ULL;

    float eff[4];
    #pragma unroll
    for (int k = 0; k < 4; ++k) eff[k] = av ? sv[k] : 0.f;

    // row max (wave shfl + 4-wave combine)
    float m = fmaxf(fmaxf(eff[0], eff[1]), fmaxf(eff[2], eff[3]));
    #pragma unroll
    for (int off = 32; off > 0; off >>= 1) m = fmaxf(m, __shfl_xor(m, off));
    __syncthreads();                 // kred reads done before wred aliasing concerns
    if (lane == 0) wred[wave] = m;
    __syncthreads();
    const float M = fmaxf(fmaxf(wred[0], wred[1]), fmaxf(wred[2], wred[3]));

    // exp + sum
    float e[4]; float s = 0.f;
    #pragma unroll
    for (int k = 0; k < 4; ++k) { e[k] = expf(eff[k] - M); s += e[k]; }
    #pragma unroll
    for (int off = 32; off > 0; off >>= 1) s += __shfl_xor(s, off);
    __syncthreads();
    if (lane == 0) wred[wave] = s;
    __syncthreads();
    const float invZ = 1.f / (wred[0] + wred[1] + wred[2] + wred[3]);

    #pragma unroll
    for (int k = 0; k < 4; ++k) {
        int i = tid + k * 256;
        float w = e[k] * invZ;
        ex[i] = w;
        out_attn[(long)b * SS + i] = w;
    }

    // top-8: packed (sortable-float, SS-1-i) u64, wave max-reduce, owner-zero
    unsigned long long key[4];
    #pragma unroll
    for (int k = 0; k < 4; ++k) {
        int i = tid + k * 256;
        unsigned ub = __float_as_uint(eff[k]);
        ub = (ub & 0x80000000u) ? ~ub : (ub | 0x80000000u);
        key[k] = ((unsigned long long)ub << 32) | (unsigned)(SS - 1 - i);
    }
    for (int r = 0; r < TOPK; ++r) {
        unsigned long long kmax = key[0];
        if (key[1] > kmax) kmax = key[1];
        if (key[2] > kmax) kmax = key[2];
        if (key[3] > kmax) kmax = key[3];
        #pragma unroll
        for (int off = 32; off > 0; off >>= 1) {
            unsigned long long o = __shfl_xor(kmax, off);
            if (o > kmax) kmax = o;
        }
        if (lane == 0) kred[wave] = kmax;
        __syncthreads();
        unsigned long long kb = kred[0];
        if (kred[1] > kb) kb = kred[1];
        if (kred[2] > kb) kb = kred[2];
        if (kred[3] > kb) kb = kred[3];
        int idx = (SS - 1) - (int)(kb & 0xffffffffu);
        if (tid == 0) selIdx[r] = idx;
        #pragma unroll
        for (int k = 0; k < 4; ++k)
            if (tid + k * 256 == idx) key[k] = 0ULL;
        __syncthreads();             // kred consumed; safe for next round
    }

    // sel gather: 8 rows x 64 channels
    for (int f = tid; f < TOPK * DSLOT; f += 256) {
        int r = f >> 6, d = f & 63;
        unsigned short hb = Hws[((long)b * SS + selIdx[r]) * DSLOT + d];
        out_sel[(long)b * (TOPK * DSLOT) + f] = bf2f(hb);
    }

    // ctx: thread (sg = tid>>4, dg = tid&15) accumulates 4 channels over 64 slots
    const int dg = tid & 15, sg = tid >> 4;
    float a0 = 0.f, a1 = 0.f, a2 = 0.f, a3 = 0.f;
    #pragma unroll 4
    for (int it = 0; it < 64; ++it) {
        int s2 = sg * 64 + it;
        uint2 u = *(const uint2*)&Hws[((long)b * SS + s2) * DSLOT + dg * 4];
        float w = ex[s2];
        a0 = fmaf(w, bf2f(u.x & 0xffffu), a0);
        a1 = fmaf(w, bf2f(u.x >> 16), a1);
        a2 = fmaf(w, bf2f(u.y & 0xffffu), a2);
        a3 = fmaf(w, bf2f(u.y >> 16), a3);
    }
    cred[sg * 64 + dg * 4 + 0] = a0;
    cred[sg * 64 + dg * 4 + 1] = a1;
    cred[sg * 64 + dg * 4 + 2] = a2;
    cred[sg * 64 + dg * 4 + 3] = a3;
    __syncthreads();
    if (tid < 64) {
        float accc = 0.f;
        #pragma unroll
        for (int g = 0; g < 16; ++g) accc += cred[g * 64 + tid];
        out_ctx[(long)b * DSLOT + tid] = accc;
    }
}

// ------------------------------------------------------------------
extern "C" void kernel_launch(void* const* d_in, const int* in_sizes, int n_in,
                              void* d_out, int out_size, void* d_ws, size_t ws_size,
                              hipStream_t stream) {
    (void)in_sizes; (void)n_in; (void)out_size; (void)ws_size;
    const float* feats = (const float*)d_in[0];
    const float* smask = (const float*)d_in[1];
    const float* W1 = (const float*)d_in[2];
    const float* b1 = (const float*)d_in[3];
    const float* W2 = (const float*)d_in[4];
    const float* b2 = (const float*)d_in[5];
    const float* q  = (const float*)d_in[6];

    // workspace: H bf16 [1M x 64] (128 MB) | scores f32 [1M] (4 MB) | vv[65]
    char* ws = (char*)d_ws;
    unsigned short* Hws = (unsigned short*)ws;
    float* scores = (float*)(ws + (size_t)TOKENS * DSLOT * 2);
    float* vv = (float*)(ws + (size_t)TOKENS * DSLOT * 2 + (size_t)TOKENS * 4);

    float* out_sel  = (float*)d_out;                       // [1024, 8, 64]
    float* out_ctx  = out_sel + (long)BB * TOPK * DSLOT;   // [1024, 64]
    float* out_attn = out_ctx + (long)BB * DSLOT;          // [1024, 1024]

    prep_kernel<<<1, 64, 0, stream>>>(W2, b2, q, vv);
    mlp_kernel<<<TOKENS / 256, 256, 0, stream>>>(feats, W1, b1, W2, b2, vv, Hws, scores);
    attn_kernel<<<BB, 256, 0, stream>>>(scores, smask, Hws, out_sel, out_ctx, out_attn);
}